// Round 8
// baseline (408.916 us; speedup 1.0000x reference)
//
#include <hip/hip_runtime.h>
#include <hip/hip_bf16.h>
#include <math.h>

#define T_SEQ 2048
#define NHEAD 16
#define DQK 192      // NOPE + ROPE
#define DNOPE 128
#define DROPE 64
#define LORA_D 512
#define VDIM 128
#define SCALE_F 0.072168783648703216f  // 1/sqrt(192)
#define KC 32

typedef short bf16x8 __attribute__((ext_vector_type(8)));   // 8 bf16 = 4 VGPRs
typedef float f32x4 __attribute__((ext_vector_type(4)));

static __device__ __forceinline__ unsigned short f2bf(float x) {
  union { float f; unsigned int u; } v; v.f = x;
  unsigned int r = (v.u + 0x7fff + ((v.u >> 16) & 1)) >> 16;  // RNE
  return (unsigned short)r;
}
static __device__ __forceinline__ unsigned int pkbf(float a, float b) {
  return (unsigned int)f2bf(a) | ((unsigned int)f2bf(b) << 16);
}

// ---------------------------------------------------------------------------
// stage_all: fused input prep. grid (1024, 3).
//  y==0: cast k_c fp32 (T,512) -> bf16 Ab
//  y==1: BkT[n][k] = bf16(w_kv_b[k][(n>>7)*256 + (n&127)])   (32x32 transpose)
//  y==2: BvT[(h*128+v)][k] = bf16(w_uv[h][k][v])             (32x32 transpose)
// ---------------------------------------------------------------------------
__global__ __launch_bounds__(256) void stage_all(
    const float* __restrict__ k_c, const float* __restrict__ w_kv_b,
    const float* __restrict__ w_uv, unsigned short* __restrict__ Ab,
    unsigned short* __restrict__ BkT, unsigned short* __restrict__ BvT)
{
  __shared__ float tile[32][33];
  const int bx = blockIdx.x, role = blockIdx.y;
  const int tid = threadIdx.x;
  if (role == 0) {
    int i = (bx * 256 + tid) * 4;
    float4 v = *(const float4*)(k_c + i);
    ushort4 o = {f2bf(v.x), f2bf(v.y), f2bf(v.z), f2bf(v.w)};
    *(ushort4*)(Ab + i) = o;
    return;
  }
  const int tk = tid >> 3, tc4 = (tid & 7) * 4;
  const int wr = tid >> 3, wk4 = (tid & 7) * 4;
  if (role == 1) {
    const int k0 = (bx & 15) * 32, n0 = (bx >> 4) * 32;
    int n = n0 + tc4;
    int col = n + ((n >> 7) << 7);   // skip VDIM half of each head's 256 cols
    float4 v = *(const float4*)&w_kv_b[(size_t)(k0 + tk) * 4096 + col];
    tile[tk][tc4 + 0] = v.x; tile[tk][tc4 + 1] = v.y;
    tile[tk][tc4 + 2] = v.z; tile[tk][tc4 + 3] = v.w;
    __syncthreads();
    ushort4 o = {f2bf(tile[wk4 + 0][wr]), f2bf(tile[wk4 + 1][wr]),
                 f2bf(tile[wk4 + 2][wr]), f2bf(tile[wk4 + 3][wr])};
    *(ushort4*)&BkT[(size_t)(n0 + wr) * LORA_D + k0 + wk4] = o;
  } else {
    const int k0 = (bx & 15) * 32, v0 = ((bx >> 4) & 3) * 32, h = bx >> 6;
    float4 v = *(const float4*)&w_uv[(size_t)h * 65536 + (size_t)(k0 + tk) * 128 + v0 + tc4];
    tile[tk][tc4 + 0] = v.x; tile[tk][tc4 + 1] = v.y;
    tile[tk][tc4 + 2] = v.z; tile[tk][tc4 + 3] = v.w;
    __syncthreads();
    ushort4 o = {f2bf(tile[wk4 + 0][wr]), f2bf(tile[wk4 + 1][wr]),
                 f2bf(tile[wk4 + 2][wr]), f2bf(tile[wk4 + 3][wr])};
    *(ushort4*)&BvT[(size_t)(h * VDIM + v0 + wr) * LORA_D + k0 + wk4] = o;
  }
}

// ---------------------------------------------------------------------------
// prep_gemm: C = Ab(2048x512) @ BT(4096x512)^T slices, bf16 in, fp32 acc.
// 128x64 tile (was 128x128) -> 1024 blocks, 4-5/CU. BK=32, double-buffered
// LDS + register prefetch, 1 barrier per chunk. grid (16, 64): by<32 ->
// K-epilogue (head by>>1, d-half by&1; rope fused on d-half 0); else V^T.
// ---------------------------------------------------------------------------
__global__ __launch_bounds__(256) void prep_gemm(
    const unsigned short* __restrict__ A, const unsigned short* __restrict__ BkT,
    const unsigned short* __restrict__ BvT, const float* __restrict__ k_pe,
    unsigned short* __restrict__ Kb, unsigned short* __restrict__ Vt)
{
  __shared__ unsigned short As[2][128][40];
  __shared__ unsigned short Bs[2][64][40];
  const int m0 = blockIdx.x * 128;
  const int by = blockIdx.y;
  const int isK = (by < 32);
  const int n0 = isK ? by * 64 : (by - 32) * 64;   // row into BkT / BvT
  const unsigned short* BT = isK ? BkT : BvT;
  const int tid = threadIdx.x;
  const int wid = tid >> 6, lane = tid & 63;
  const int l16 = lane & 15, quad = lane >> 4;
  const int wm = wid * 32;
  const int arow = tid >> 2, asc = tid & 3;
  const int brow = tid >> 2, bsc = tid & 3;
  uint4 areg[2], breg;

  auto load_regs = [&](int k0) {
#pragma unroll
    for (int i = 0; i < 2; ++i)
      areg[i] = *(const uint4*)(A + (size_t)(m0 + arow + i * 64) * LORA_D + k0 + asc * 8);
    breg = *(const uint4*)(BT + (size_t)(n0 + brow) * LORA_D + k0 + bsc * 8);
  };
  auto store_lds = [&](int b) {
#pragma unroll
    for (int i = 0; i < 2; ++i)
      *(uint4*)((char*)&As[b][arow + i * 64][0] + asc * 16) = areg[i];
    *(uint4*)((char*)&Bs[b][brow][0] + bsc * 16) = breg;
  };

  f32x4 acc[2][4];
#pragma unroll
  for (int i = 0; i < 2; ++i)
#pragma unroll
    for (int j = 0; j < 4; ++j) acc[i][j] = (f32x4){0.f, 0.f, 0.f, 0.f};

  load_regs(0);
  store_lds(0);
  __syncthreads();
  for (int kc = 0; kc < 16; ++kc) {
    const int cur = kc & 1;
    if (kc < 15) load_regs((kc + 1) * 32);
    bf16x8 af[2], bfr[4];
#pragma unroll
    for (int t = 0; t < 2; ++t)
      af[t] = *(const bf16x8*)&As[cur][wm + t * 16 + l16][quad * 8];
#pragma unroll
    for (int t = 0; t < 4; ++t)
      bfr[t] = *(const bf16x8*)&Bs[cur][t * 16 + l16][quad * 8];
#pragma unroll
    for (int mt = 0; mt < 2; ++mt)
#pragma unroll
      for (int nt = 0; nt < 4; ++nt)
        acc[mt][nt] = __builtin_amdgcn_mfma_f32_16x16x32_bf16(af[mt], bfr[nt], acc[mt][nt], 0, 0, 0);
    if (kc < 15) store_lds(cur ^ 1);
    __syncthreads();
  }

  if (isK) {
    const int h = by >> 1;
    const int dbase = (by & 1) * 64;
#pragma unroll
    for (int mt = 0; mt < 2; ++mt)
#pragma unroll
      for (int nt = 0; nt < 4; ++nt) {
        int m = m0 + wm + mt * 16 + quad * 4;
        int d = dbase + nt * 16 + l16;
#pragma unroll
        for (int r = 0; r < 4; ++r)
          Kb[(size_t)h * (T_SEQ * DQK) + (size_t)(m + r) * DQK + d] =
              f2bf(acc[mt][nt][r]);
      }
    if (dbase == 0) {  // fused rope, once per (h, m0)
      for (int e = tid; e < 128 * 16; e += 256) {
        int row = e >> 4, c4 = (e & 15) * 4;
        float4 v = *(const float4*)&k_pe[(size_t)(m0 + row) * DROPE + c4];
        ushort4 o = {f2bf(v.x), f2bf(v.y), f2bf(v.z), f2bf(v.w)};
        *(ushort4*)&Kb[(size_t)h * (T_SEQ * DQK) + (size_t)(m0 + row) * DQK + DNOPE + c4] = o;
      }
    }
  } else {
#pragma unroll
    for (int mt = 0; mt < 2; ++mt)
#pragma unroll
      for (int nt = 0; nt < 4; ++nt) {
        int n = n0 + nt * 16 + l16;
        int m = m0 + wm + mt * 16 + quad * 4;
        ushort4 o = {f2bf(acc[mt][nt][0]), f2bf(acc[mt][nt][1]),
                     f2bf(acc[mt][nt][2]), f2bf(acc[mt][nt][3])};
        *(ushort4*)&Vt[(size_t)n * T_SEQ + m] = o;
      }
  }
}

// ---------------------------------------------------------------------------
// flash_mfma: block = (head, 128-row q-tile, <=8-chunk key segment); 1152
// balanced blocks. 4 waves, wave wid owns 32 q-rows. LDS-staged K/V double
// buffer (R5-verified), 1 barrier/chunk. Transposed MFMA:
//   S^T = K @ Q^T   (A=K frag from LDS, B=Q frag direct-global once)
//   O^T = V^T @ P^T (A=V^T frag from LDS, B=P^T built in-register via the
//                    R7-verified 8-shfl transform; no P LDS round-trip)
// 40 MFMA per wave-chunk vs 20 LDS reads (2x R5 density, same staging bytes).
// No-max softmax => split-K partials combine additively via atomics.
// ---------------------------------------------------------------------------
__global__ __launch_bounds__(256, 2) void flash_mfma(
    const float* __restrict__ Q, const unsigned short* __restrict__ K,
    const unsigned short* __restrict__ Vt, float* __restrict__ outp,
    float* __restrict__ lacc)
{
  __shared__ unsigned short Ks[2][KC][200];
  __shared__ unsigned short Vs[2][128][40];
  const int id = blockIdx.x;
  const int hh = id & 15;
  const int h = ((hh & 7) << 1) | (hh >> 3);    // spread heads across XCDs
  int u = id >> 4;                               // 0..71 per head, heavy first
  int t = 15, seg = 0;
  {
    int acc = 0;
    for (int tt = 15; tt >= 0; --tt) {
      int ns = (4 * (tt + 1) + 7) >> 3;
      if (u < acc + ns) { t = tt; seg = u - acc; break; }
      acc += ns;
    }
  }
  const int q0 = t * 128;
  const int cbeg = seg * 8;
  const int ctot = 4 * (t + 1);
  const int cend = (cbeg + 8 < ctot) ? cbeg + 8 : ctot;

  const int tid = threadIdx.x;
  const int wid = tid >> 6;
  const int lane = tid & 63;
  const int l16 = lane & 15;
  const int quad = lane >> 4;
  const int qt0 = q0 + wid * 32;

  const unsigned short* Kh  = K  + (size_t)h * T_SEQ * DQK;
  const unsigned short* Vth = Vt + (size_t)h * VDIM * T_SEQ;

  // ---- Q B-frags direct from global (n=l16 -> q-row, k=quad*8+j -> dim) ----
  bf16x8 qf[2][6];
#pragma unroll
  for (int nt = 0; nt < 2; ++nt) {
    const float* qp = Q + (size_t)(qt0 + nt * 16 + l16) * (NHEAD * DQK) + h * DQK;
#pragma unroll
    for (int ks = 0; ks < 6; ++ks) {
      float4 a = *(const float4*)(qp + ks * 32 + quad * 8);
      float4 b = *(const float4*)(qp + ks * 32 + quad * 8 + 4);
      union { bf16x8 v; unsigned int u[4]; } tt;
      tt.u[0] = pkbf(a.x, a.y); tt.u[1] = pkbf(a.z, a.w);
      tt.u[2] = pkbf(b.x, b.y); tt.u[3] = pkbf(b.z, b.w);
      qf[nt][ks] = tt.v;
    }
  }

  uint4 kreg[3], vreg[2];
  auto load_regs = [&](int s0) {
#pragma unroll
    for (int i = 0; i < 3; ++i) {
      int s = tid + i * 256, row = s / 24, c = s - row * 24;
      kreg[i] = *(const uint4*)(Kh + (size_t)(s0 + row) * DQK + c * 8);
    }
#pragma unroll
    for (int i = 0; i < 2; ++i) {
      int s = tid + i * 256, row = s >> 2, c = s & 3;
      vreg[i] = *(const uint4*)(Vth + (size_t)row * T_SEQ + s0 + c * 8);
    }
  };
  auto store_lds = [&](int b) {
#pragma unroll
    for (int i = 0; i < 3; ++i) {
      int s = tid + i * 256, row = s / 24, c = s - row * 24;
      *(uint4*)((char*)&Ks[b][row][0] + c * 16) = kreg[i];
    }
#pragma unroll
    for (int i = 0; i < 2; ++i) {
      int s = tid + i * 256, row = s >> 2, c = s & 3;
      *(uint4*)((char*)&Vs[b][row][0] + c * 16) = vreg[i];
    }
  };

  f32x4 oacc[8][2];
#pragma unroll
  for (int i = 0; i < 8; ++i)
#pragma unroll
    for (int j = 0; j < 2; ++j) oacc[i][j] = (f32x4){0.f, 0.f, 0.f, 0.f};
  float lsum[2] = {0.f, 0.f};

  const int L0 = ((quad & 1) << 5) + l16;   // R7-verified transform lanes
  const int L1 = L0 + 16;

  load_regs(cbeg * KC);
  store_lds(0);
  __syncthreads();

  for (int kb = cbeg; kb < cend; ++kb) {
    const int cur = (kb - cbeg) & 1;
    const int s0 = kb * KC;
    if (kb + 1 < cend) load_regs(s0 + KC);

    // ---- S^T = K @ Q^T : 2 key-tiles x 2 q-tiles ----
    f32x4 sacc[2][2];
#pragma unroll
    for (int kt = 0; kt < 2; ++kt)
#pragma unroll
      for (int nt = 0; nt < 2; ++nt) sacc[kt][nt] = (f32x4){0.f, 0.f, 0.f, 0.f};
#pragma unroll
    for (int ks = 0; ks < 6; ++ks) {
      bf16x8 kf0 = *(const bf16x8*)&Ks[cur][l16][ks * 32 + quad * 8];
      bf16x8 kf1 = *(const bf16x8*)&Ks[cur][16 + l16][ks * 32 + quad * 8];
      sacc[0][0] = __builtin_amdgcn_mfma_f32_16x16x32_bf16(kf0, qf[0][ks], sacc[0][0], 0, 0, 0);
      sacc[0][1] = __builtin_amdgcn_mfma_f32_16x16x32_bf16(kf0, qf[1][ks], sacc[0][1], 0, 0, 0);
      sacc[1][0] = __builtin_amdgcn_mfma_f32_16x16x32_bf16(kf1, qf[0][ks], sacc[1][0], 0, 0, 0);
      sacc[1][1] = __builtin_amdgcn_mfma_f32_16x16x32_bf16(kf1, qf[1][ks], sacc[1][1], 0, 0, 0);
    }

    // ---- exp + mask + in-register P^T transform (per q-tile) ----
    bf16x8 pb[2];
#pragma unroll
    for (int nt = 0; nt < 2; ++nt) {
      const int qrow = qt0 + nt * 16 + l16;
      float ps[2][4];
#pragma unroll
      for (int kt = 0; kt < 2; ++kt)
#pragma unroll
        for (int r = 0; r < 4; ++r) {
          int kidx = s0 + kt * 16 + quad * 4 + r;
          float p = (kidx <= qrow) ? __expf(sacc[kt][nt][r] * SCALE_F) : 0.f;
          lsum[nt] += p;
          ps[kt][r] = p;
        }
      unsigned int t00 = pkbf(ps[0][0], ps[0][1]);
      unsigned int t01 = pkbf(ps[0][2], ps[0][3]);
      unsigned int t10 = pkbf(ps[1][0], ps[1][1]);
      unsigned int t11 = pkbf(ps[1][2], ps[1][3]);
      unsigned int a0 = __shfl((int)t00, L0), b0 = __shfl((int)t10, L0);
      unsigned int a1 = __shfl((int)t01, L0), b1 = __shfl((int)t11, L0);
      unsigned int a2 = __shfl((int)t00, L1), b2 = __shfl((int)t10, L1);
      unsigned int a3 = __shfl((int)t01, L1), b3 = __shfl((int)t11, L1);
      union { bf16x8 v; unsigned int u[4]; } pbu;
      pbu.u[0] = (quad < 2) ? a0 : b0;
      pbu.u[1] = (quad < 2) ? a1 : b1;
      pbu.u[2] = (quad < 2) ? a2 : b2;
      pbu.u[3] = (quad < 2) ? a3 : b3;
      pb[nt] = pbu.v;
    }

    // ---- O^T += V^T @ P^T ----
#pragma unroll
    for (int mt = 0; mt < 8; ++mt) {
      bf16x8 vf = *(const bf16x8*)&Vs[cur][mt * 16 + l16][quad * 8];
      oacc[mt][0] = __builtin_amdgcn_mfma_f32_16x16x32_bf16(vf, pb[0], oacc[mt][0], 0, 0, 0);
      oacc[mt][1] = __builtin_amdgcn_mfma_f32_16x16x32_bf16(vf, pb[1], oacc[mt][1], 0, 0, 0);
    }

    if (kb + 1 < cend) store_lds(cur ^ 1);
    __syncthreads();
  }

  // ---- combine: l over quads; unnormalized O^T via device atomics ----
#pragma unroll
  for (int nt = 0; nt < 2; ++nt) {
    lsum[nt] += __shfl_xor(lsum[nt], 16);
    lsum[nt] += __shfl_xor(lsum[nt], 32);
  }
  if (quad == 0) {
    atomicAdd(&lacc[(qt0 + l16) * NHEAD + h], lsum[0]);
    atomicAdd(&lacc[(qt0 + 16 + l16) * NHEAD + h], lsum[1]);
  }
#pragma unroll
  for (int mt = 0; mt < 8; ++mt)
#pragma unroll
    for (int nt = 0; nt < 2; ++nt)
#pragma unroll
      for (int r = 0; r < 4; ++r)
        atomicAdd(&outp[(size_t)(qt0 + nt * 16 + l16) * (NHEAD * VDIM) + h * VDIM +
                        mt * 16 + quad * 4 + r],
                  oacc[mt][nt][r]);
}

// ---------------------------------------------------------------------------
// norm_out: out[t][h*128+v] /= l[t][h]
// ---------------------------------------------------------------------------
__global__ __launch_bounds__(256) void norm_out(
    float* __restrict__ outp, const float* __restrict__ lacc)
{
  int e = (blockIdx.x * 256 + threadIdx.x) * 4;
  int t = e >> 11;
  int hh = (e >> 7) & 15;
  float inv = 1.f / lacc[t * NHEAD + hh];
  float4 v = *(float4*)(outp + e);
  v.x *= inv; v.y *= inv; v.z *= inv; v.w *= inv;
  *(float4*)(outp + e) = v;
}

// ---------------------------------------------------------------------------
extern "C" void kernel_launch(void* const* d_in, const int* in_sizes, int n_in,
                              void* d_out, int out_size, void* d_ws, size_t ws_size,
                              hipStream_t stream) {
  const float* query  = (const float*)d_in[0];  // (T, H, 192)
  const float* k_c    = (const float*)d_in[1];  // (T, 512)
  const float* k_pe   = (const float*)d_in[2];  // (T, 64)
  const float* w_kv_b = (const float*)d_in[3];  // (512, 4096)
  const float* w_uv   = (const float*)d_in[4];  // (16, 512, 128)
  float* outp = (float*)d_out;                  // (T, 2048)

  unsigned short* Kb  = (unsigned short*)d_ws;             // (H,T,192) bf16
  unsigned short* Vt  = Kb + (size_t)NHEAD * T_SEQ * DQK;  // (H,128,T) bf16
  unsigned short* Ab  = Vt + (size_t)NHEAD * VDIM * T_SEQ; // (T,512)
  unsigned short* BkT = Ab + (size_t)T_SEQ * LORA_D;       // (2048,512)
  unsigned short* BvT = BkT + (size_t)2048 * LORA_D;       // (2048,512)
  float* lacc = (float*)(BvT + (size_t)2048 * LORA_D);     // (T,16) fp32

  hipMemsetAsync(outp, 0, (size_t)T_SEQ * NHEAD * VDIM * sizeof(float), stream);
  hipMemsetAsync(lacc, 0, (size_t)T_SEQ * NHEAD * sizeof(float), stream);

  stage_all<<<dim3(1024, 3), 256, 0, stream>>>(k_c, w_kv_b, w_uv, Ab, BkT, BvT);
  prep_gemm<<<dim3(16, 64), 256, 0, stream>>>(Ab, BkT, BvT, k_pe, Kb, Vt);
  flash_mfma<<<1152, 256, 0, stream>>>(query, Kb, Vt, outp, lacc);
  norm_out<<<T_SEQ * NHEAD * VDIM / 1024, 256, 0, stream>>>(outp, lacc);
}

// Round 9
// 267.603 us; speedup vs baseline: 1.5281x; 1.5281x over previous
//
#include <hip/hip_runtime.h>
#include <hip/hip_bf16.h>
#include <math.h>

#define T_SEQ 2048
#define NHEAD 16
#define DQK 192      // NOPE + ROPE
#define DNOPE 128
#define DROPE 64
#define LORA_D 512
#define VDIM 128
#define SCALE_F 0.072168783648703216f  // 1/sqrt(192)
#define KC 32

typedef short bf16x8 __attribute__((ext_vector_type(8)));   // 8 bf16 = 4 VGPRs
typedef float f32x4 __attribute__((ext_vector_type(4)));

static __device__ __forceinline__ unsigned short f2bf(float x) {
  union { float f; unsigned int u; } v; v.f = x;
  unsigned int r = (v.u + 0x7fff + ((v.u >> 16) & 1)) >> 16;  // RNE
  return (unsigned short)r;
}

// ---------------------------------------------------------------------------
// stage_all: fused input prep. grid (1024, 3).  [R5-proven]
//  y==0: cast k_c fp32 (T,512) -> bf16 Ab
//  y==1: BkT[n][k] = bf16(w_kv_b[k][(n>>7)*256 + (n&127)])   (32x32 transpose)
//  y==2: BvT[(h*128+v)][k] = bf16(w_uv[h][k][v])             (32x32 transpose)
// ---------------------------------------------------------------------------
__global__ __launch_bounds__(256) void stage_all(
    const float* __restrict__ k_c, const float* __restrict__ w_kv_b,
    const float* __restrict__ w_uv, unsigned short* __restrict__ Ab,
    unsigned short* __restrict__ BkT, unsigned short* __restrict__ BvT)
{
  __shared__ float tile[32][33];
  const int bx = blockIdx.x, role = blockIdx.y;
  const int tid = threadIdx.x;
  if (role == 0) {
    int i = (bx * 256 + tid) * 4;
    float4 v = *(const float4*)(k_c + i);
    ushort4 o = {f2bf(v.x), f2bf(v.y), f2bf(v.z), f2bf(v.w)};
    *(ushort4*)(Ab + i) = o;
    return;
  }
  const int tk = tid >> 3, tc4 = (tid & 7) * 4;
  const int wr = tid >> 3, wk4 = (tid & 7) * 4;
  if (role == 1) {
    const int k0 = (bx & 15) * 32, n0 = (bx >> 4) * 32;
    int n = n0 + tc4;
    int col = n + ((n >> 7) << 7);   // skip VDIM half of each head's 256 cols
    float4 v = *(const float4*)&w_kv_b[(size_t)(k0 + tk) * 4096 + col];
    tile[tk][tc4 + 0] = v.x; tile[tk][tc4 + 1] = v.y;
    tile[tk][tc4 + 2] = v.z; tile[tk][tc4 + 3] = v.w;
    __syncthreads();
    ushort4 o = {f2bf(tile[wk4 + 0][wr]), f2bf(tile[wk4 + 1][wr]),
                 f2bf(tile[wk4 + 2][wr]), f2bf(tile[wk4 + 3][wr])};
    *(ushort4*)&BkT[(size_t)(n0 + wr) * LORA_D + k0 + wk4] = o;
  } else {
    const int k0 = (bx & 15) * 32, v0 = ((bx >> 4) & 3) * 32, h = bx >> 6;
    float4 v = *(const float4*)&w_uv[(size_t)h * 65536 + (size_t)(k0 + tk) * 128 + v0 + tc4];
    tile[tk][tc4 + 0] = v.x; tile[tk][tc4 + 1] = v.y;
    tile[tk][tc4 + 2] = v.z; tile[tk][tc4 + 3] = v.w;
    __syncthreads();
    ushort4 o = {f2bf(tile[wk4 + 0][wr]), f2bf(tile[wk4 + 1][wr]),
                 f2bf(tile[wk4 + 2][wr]), f2bf(tile[wk4 + 3][wr])};
    *(ushort4*)&BvT[(size_t)(h * VDIM + v0 + wr) * LORA_D + k0 + wk4] = o;
  }
}

// ---------------------------------------------------------------------------
// prep_gemm: C(2048x2048) = Ab(2048x512) @ BT(2048x512)^T, bf16 in, fp32 acc.
// [R5-proven] 128x128 tile, BK=32, double-buffered LDS + register prefetch,
// 1 barrier/chunk. grid (16, 32): by<16 -> K-epilogue (head by) + fused rope;
// by>=16 -> V^T epilogue.
// ---------------------------------------------------------------------------
__global__ __launch_bounds__(256) void prep_gemm(
    const unsigned short* __restrict__ A, const unsigned short* __restrict__ BkT,
    const unsigned short* __restrict__ BvT, const float* __restrict__ k_pe,
    unsigned short* __restrict__ Kb, unsigned short* __restrict__ Vt)
{
  __shared__ unsigned short As[2][128][40];
  __shared__ unsigned short Bs[2][128][40];
  const int m0 = blockIdx.x * 128;
  const int by = blockIdx.y;
  const int isK = (by < 16);
  const int n0 = (isK ? by : (by - 16)) * 128;
  const unsigned short* BT = isK ? BkT : BvT;
  const int tid = threadIdx.x;
  const int wid = tid >> 6, lane = tid & 63;
  const int l16 = lane & 15, quad = lane >> 4;
  const int wm = (wid >> 1) * 64, wn = (wid & 1) * 64;
  const int srow = tid >> 2, sc = tid & 3;
  uint4 areg[2], breg[2];

  auto load_regs = [&](int k0) {
#pragma unroll
    for (int i = 0; i < 2; ++i) {
      int row = srow + i * 64;
      areg[i] = *(const uint4*)(A + (size_t)(m0 + row) * LORA_D + k0 + sc * 8);
      breg[i] = *(const uint4*)(BT + (size_t)(n0 + row) * LORA_D + k0 + sc * 8);
    }
  };
  auto store_lds = [&](int b) {
#pragma unroll
    for (int i = 0; i < 2; ++i) {
      int row = srow + i * 64;
      *(uint4*)((char*)&As[b][row][0] + sc * 16) = areg[i];
      *(uint4*)((char*)&Bs[b][row][0] + sc * 16) = breg[i];
    }
  };

  f32x4 acc[4][4];
#pragma unroll
  for (int i = 0; i < 4; ++i)
#pragma unroll
    for (int j = 0; j < 4; ++j) acc[i][j] = (f32x4){0.f, 0.f, 0.f, 0.f};

  load_regs(0);
  store_lds(0);
  __syncthreads();
  for (int kc = 0; kc < 16; ++kc) {
    const int cur = kc & 1;
    if (kc < 15) load_regs((kc + 1) * 32);
    bf16x8 af[4], bfr[4];
#pragma unroll
    for (int t = 0; t < 4; ++t) {
      af[t] = *(const bf16x8*)&As[cur][wm + t * 16 + l16][quad * 8];
      bfr[t] = *(const bf16x8*)&Bs[cur][wn + t * 16 + l16][quad * 8];
    }
#pragma unroll
    for (int mt = 0; mt < 4; ++mt)
#pragma unroll
      for (int nt = 0; nt < 4; ++nt)
        acc[mt][nt] = __builtin_amdgcn_mfma_f32_16x16x32_bf16(af[mt], bfr[nt], acc[mt][nt], 0, 0, 0);
    if (kc < 15) store_lds(cur ^ 1);
    __syncthreads();
  }

  if (isK) {
    const int h = by;
#pragma unroll
    for (int mt = 0; mt < 4; ++mt)
#pragma unroll
      for (int nt = 0; nt < 4; ++nt) {
        int m = m0 + wm + mt * 16 + quad * 4;
        int d = wn + nt * 16 + l16;
#pragma unroll
        for (int r = 0; r < 4; ++r)
          Kb[(size_t)h * (T_SEQ * DQK) + (size_t)(m + r) * DQK + d] =
              f2bf(acc[mt][nt][r]);
      }
    // fused rope: Kb[h][m0+row][128+c] = bf16(k_pe[m0+row][c])
    for (int e = tid; e < 128 * 16; e += 256) {
      int row = e >> 4, c4 = (e & 15) * 4;
      float4 v = *(const float4*)&k_pe[(size_t)(m0 + row) * DROPE + c4];
      ushort4 o = {f2bf(v.x), f2bf(v.y), f2bf(v.z), f2bf(v.w)};
      *(ushort4*)&Kb[(size_t)h * (T_SEQ * DQK) + (size_t)(m0 + row) * DQK + DNOPE + c4] = o;
    }
  } else {
#pragma unroll
    for (int mt = 0; mt < 4; ++mt)
#pragma unroll
      for (int nt = 0; nt < 4; ++nt) {
        int n = n0 + wn + nt * 16 + l16;
        int m = m0 + wm + mt * 16 + quad * 4;
        ushort4 o = {f2bf(acc[mt][nt][0]), f2bf(acc[mt][nt][1]),
                     f2bf(acc[mt][nt][2]), f2bf(acc[mt][nt][3])};
        *(ushort4*)&Vt[(size_t)n * T_SEQ + m] = o;
      }
  }
}

// ---------------------------------------------------------------------------
// flash_mfma: best-of-session assembly. Block = (head, 64 q-rows), 4 waves,
// full causal key range per block (R3 loop, NO split-K / NO atomics), LDS
// K-dbuf unioned with Q staging + V-dbuf + P (51.2 KB -> 3 blocks/CU, R5
// layout), register prefetch, 1 barrier/chunk, no-max softmax, in-kernel
// normalize + direct coalesced-ish stores (R3 epilogue).
// ---------------------------------------------------------------------------
__global__ __launch_bounds__(256, 3) void flash_mfma(
    const float* __restrict__ Q, const unsigned short* __restrict__ K,
    const unsigned short* __restrict__ Vt, float* __restrict__ outp)
{
  __shared__ unsigned short SM[2 * KC * 200];   // union: Qs[64][200] / Ks[2][32][200]
  __shared__ unsigned short Vs[2][128][40];
  __shared__ unsigned short Ps[4][16][40];
  const int id = blockIdx.x;
  const int h = ((id & 7) << 1) | ((id >> 3) & 1);   // cluster heads per XCD
  const int q0 = (31 - (id >> 4)) * 64;              // heavy tiles first
  const int tid = threadIdx.x;
  const int wid = tid >> 6;
  const int lane = tid & 63;
  const int l16 = lane & 15;
  const int quad = lane >> 4;

  const unsigned short* Kh = K + (size_t)h * T_SEQ * DQK;
  const unsigned short* Vth = Vt + (size_t)h * VDIM * T_SEQ;

  uint4 kreg[3], vreg[2];
  auto load_regs = [&](int s0) {
#pragma unroll
    for (int i = 0; i < 3; ++i) {
      int s = tid + i * 256, row = s / 24, c = s - row * 24;
      kreg[i] = *(const uint4*)(Kh + (size_t)(s0 + row) * DQK + c * 8);
    }
#pragma unroll
    for (int i = 0; i < 2; ++i) {
      int s = tid + i * 256, row = s >> 2, c = s & 3;
      vreg[i] = *(const uint4*)(Vth + (size_t)row * T_SEQ + s0 + c * 8);
    }
  };
  auto store_lds = [&](int b) {
#pragma unroll
    for (int i = 0; i < 3; ++i) {
      int s = tid + i * 256, row = s / 24, c = s - row * 24;
      *(uint4*)((char*)&SM[b * (KC * 200) + row * 200] + c * 16) = kreg[i];
    }
#pragma unroll
    for (int i = 0; i < 2; ++i) {
      int s = tid + i * 256, row = s >> 2, c = s & 3;
      *(uint4*)((char*)&Vs[b][row][0] + c * 16) = vreg[i];
    }
  };

  // ---- prefetch chunk 0 while staging Q through the SM region ----
  load_regs(0);
  for (int e = tid; e < 64 * 48; e += 256) {
    int row = e / 48, col = (e % 48) * 4;
    float4 q4 = *(const float4*)&Q[(size_t)(q0 + row) * (NHEAD * DQK) + h * DQK + col];
    ushort4 qp = {f2bf(q4.x), f2bf(q4.y), f2bf(q4.z), f2bf(q4.w)};
    *(ushort4*)&SM[row * 200 + col] = qp;
  }
  __syncthreads();
  bf16x8 qf[6];
#pragma unroll
  for (int ks = 0; ks < 6; ++ks)
    qf[ks] = *(const bf16x8*)&SM[(wid * 16 + l16) * 200 + ks * 32 + quad * 8];
  __syncthreads();           // Q reads done before region becomes Ks
  store_lds(0);
  __syncthreads();           // buffers 0 visible

  f32x4 oacc[8];
#pragma unroll
  for (int i = 0; i < 8; ++i) oacc[i] = (f32x4){0.f, 0.f, 0.f, 0.f};
  float lsum[4] = {0.f, 0.f, 0.f, 0.f};
  const int myrow = q0 + wid * 16 + quad * 4;

  const int nchunk = q0 / KC + 2;
  for (int kb = 0; kb < nchunk; ++kb) {
    const int cur = kb & 1;
    const int s0 = kb * KC;
    if (kb + 1 < nchunk) load_regs(s0 + KC);

    // ---- S = Q @ K^T ----
    f32x4 sacc[2];
    sacc[0] = (f32x4){0.f, 0.f, 0.f, 0.f};
    sacc[1] = (f32x4){0.f, 0.f, 0.f, 0.f};
#pragma unroll
    for (int ks = 0; ks < 6; ++ks) {
      bf16x8 kf0 = *(const bf16x8*)&SM[cur * (KC * 200) + l16 * 200 + ks * 32 + quad * 8];
      bf16x8 kf1 = *(const bf16x8*)&SM[cur * (KC * 200) + (16 + l16) * 200 + ks * 32 + quad * 8];
      sacc[0] = __builtin_amdgcn_mfma_f32_16x16x32_bf16(qf[ks], kf0, sacc[0], 0, 0, 0);
      sacc[1] = __builtin_amdgcn_mfma_f32_16x16x32_bf16(qf[ks], kf1, sacc[1], 0, 0, 0);
    }

    // ---- p = exp(s) (no max-subtraction; scores bounded), mask via p=0 ----
#pragma unroll
    for (int r = 0; r < 4; ++r) {
      int row = myrow + r;
      float p0 = (s0 + l16 <= row) ? __expf(sacc[0][r] * SCALE_F) : 0.f;
      float p1 = (s0 + 16 + l16 <= row) ? __expf(sacc[1][r] * SCALE_F) : 0.f;
      lsum[r] += p0 + p1;
      Ps[wid][quad * 4 + r][l16] = f2bf(p0);
      Ps[wid][quad * 4 + r][16 + l16] = f2bf(p1);
    }

    // ---- PV (P wave-private; same-wave DS ordering suffices) ----
    bf16x8 pf = *(const bf16x8*)&Ps[wid][l16][quad * 8];
#pragma unroll
    for (int nt = 0; nt < 8; ++nt) {
      bf16x8 vf = *(const bf16x8*)&Vs[cur][nt * 16 + l16][quad * 8];
      oacc[nt] = __builtin_amdgcn_mfma_f32_16x16x32_bf16(pf, vf, oacc[nt], 0, 0, 0);
    }

    if (kb + 1 < nchunk) store_lds(cur ^ 1);
    __syncthreads();
  }

  // ---- reduce l across the 16 lanes of each quad-row group; normalize ----
#pragma unroll
  for (int off = 1; off < 16; off <<= 1)
#pragma unroll
    for (int r = 0; r < 4; ++r) lsum[r] += __shfl_xor(lsum[r], off);
  float inv[4];
#pragma unroll
  for (int r = 0; r < 4; ++r) inv[r] = 1.f / lsum[r];
#pragma unroll
  for (int nt = 0; nt < 8; ++nt)
#pragma unroll
    for (int r = 0; r < 4; ++r)
      outp[(size_t)(myrow + r) * (NHEAD * VDIM) + h * VDIM + nt * 16 + l16] =
          oacc[nt][r] * inv[r];
}

// ---------------------------------------------------------------------------
extern "C" void kernel_launch(void* const* d_in, const int* in_sizes, int n_in,
                              void* d_out, int out_size, void* d_ws, size_t ws_size,
                              hipStream_t stream) {
  const float* query  = (const float*)d_in[0];  // (T, H, 192)
  const float* k_c    = (const float*)d_in[1];  // (T, 512)
  const float* k_pe   = (const float*)d_in[2];  // (T, 64)
  const float* w_kv_b = (const float*)d_in[3];  // (512, 4096)
  const float* w_uv   = (const float*)d_in[4];  // (16, 512, 128)
  float* outp = (float*)d_out;                  // (T, 2048)

  unsigned short* Kb  = (unsigned short*)d_ws;             // (H,T,192) bf16
  unsigned short* Vt  = Kb + (size_t)NHEAD * T_SEQ * DQK;  // (H,128,T) bf16
  unsigned short* Ab  = Vt + (size_t)NHEAD * VDIM * T_SEQ; // (T,512)
  unsigned short* BkT = Ab + (size_t)T_SEQ * LORA_D;       // (2048,512)
  unsigned short* BvT = BkT + (size_t)2048 * LORA_D;       // (2048,512)

  stage_all<<<dim3(1024, 3), 256, 0, stream>>>(k_c, w_kv_b, w_uv, Ab, BkT, BvT);
  prep_gemm<<<dim3(16, 32), 256, 0, stream>>>(Ab, BkT, BvT, k_pe, Kb, Vt);
  flash_mfma<<<512, 256, 0, stream>>>(query, Kb, Vt, outp);
}